// Round 7
// baseline (309.960 us; speedup 1.0000x reference)
//
#include <hip/hip_runtime.h>
#include <math.h>

#define B_ 4
#define C_ 8
#define H_ 192
#define W_ 256
#define HW_ (H_*W_)
#define SP_ 258                 // padded row stride (1 left + 1 right replicate)
#define HPLANE_ (H_*SP_)
#define GEOMW 0.01f
#define HUBER 0.5f
#define LMEPS 1e-6f

// ws layout (floats)
#define IPAD_SZ (B_*C_*HPLANE_)          // 1,585,152
#define VN_SZ   (B_*HW_*4)               //   786,432
#define ACC_SZ  (3*B_*32)
#define CNT_SZ  16
#define POSE_SZ (B_*16)

typedef float f4a __attribute__((ext_vector_type(4), aligned(4)));
typedef float f2a __attribute__((ext_vector_type(2), aligned(4)));
typedef float f4v __attribute__((ext_vector_type(4), aligned(16)));

// normals -> packed (nx,ny,nz,d0); edge-replicated padded I0 copy; zero acc/cnt; pose copy
__global__ void precompute_kernel(const float* __restrict__ I0,
                                  const float* __restrict__ depth0,
                                  const float* __restrict__ intr,
                                  const float* __restrict__ pose0,
                                  float* __restrict__ Ipad,
                                  float* __restrict__ VN,
                                  float* __restrict__ acc,
                                  unsigned int* __restrict__ cnt,
                                  float* __restrict__ poseb) {
    int idx = blockIdx.x * blockDim.x + threadIdx.x;
    if (idx < ACC_SZ) acc[idx] = 0.f;
    if (idx < CNT_SZ) cnt[idx] = 0u;
    if (idx < POSE_SZ) poseb[idx] = pose0[idx];
    if (idx >= B_ * HW_) return;
    int b = idx / HW_;
    int p = idx - b * HW_;
    int h = p >> 8;
    int w = p & 255;
    float fx = intr[b*4+0], fy = intr[b*4+1], cx = intr[b*4+2], cy = intr[b*4+3];
    const float* d = depth0 + b * HW_;
    int wl = max(w-1, 0), wr = min(w+1, W_-1);
    int hu = max(h-1, 0), hd = min(h+1, H_-1);
    float dr = d[h*W_ + wr], dl = d[h*W_ + wl];
    float dd = d[hd*W_ + w], du_ = d[hu*W_ + w];
    float pxr = ((float)wr - cx)/fx, pxl = ((float)wl - cx)/fx;
    float pyh = ((float)h  - cy)/fy;
    float pxw = ((float)w  - cx)/fx;
    float pyd = ((float)hd - cy)/fy, pyu = ((float)hu - cy)/fy;
    float dxx = 0.5f*(pxr*dr - pxl*dl), dxy = 0.5f*(pyh*dr - pyh*dl), dxz = 0.5f*(dr - dl);
    float dyx = 0.5f*(pxw*dd - pxw*du_), dyy = 0.5f*(pyd*dd - pyu*du_), dyz = 0.5f*(dd - du_);
    float n0 = dxy*dyz - dxz*dyy;
    float n1 = dxz*dyx - dxx*dyz;
    float n2 = dxx*dyy - dxy*dyx;
    float inv = 1.0f / sqrtf(n0*n0 + n1*n1 + n2*n2 + 1e-12f);
    f4v vn; vn.x = n0*inv; vn.y = n1*inv; vn.z = n2*inv; vn.w = d[p];
    *(f4v*)(VN + (size_t)(b*HW_ + p)*4) = vn;
    // padded copy of all 8 channels for this pixel
#pragma unroll
    for (int c = 0; c < C_; c++) {
        const float val = I0[((b*C_ + c)*H_ + h)*W_ + w];
        float* dst = Ipad + ((b*C_ + c)*H_ + h)*SP_ + 1 + w;
        *dst = val;
        if (w == 0)      dst[-1] = val;
        if (w == W_-1)   dst[1]  = val;
    }
}

__device__ __forceinline__ void solve_one(float* __restrict__ accb,
                                          float* __restrict__ poseb,
                                          float* __restrict__ outb) {
    float av[27];
#pragma unroll
    for (int k = 0; k < 27; k++) av[k] = atomicAdd(&accb[k], 0.0f);  // coherent read
    float M[6][7];
    {
        int cntk = 0;
        float Hm[6][6];
        for (int i = 0; i < 6; i++)
            for (int j = i; j < 6; j++) { Hm[i][j] = av[cntk]; Hm[j][i] = av[cntk]; cntk++; }
        for (int i = 0; i < 6; i++) {
            for (int j = 0; j < 6; j++) M[i][j] = Hm[i][j];
            M[i][i] += LMEPS;
            M[i][6] = av[21+i];
        }
    }
    for (int k = 0; k < 6; k++) {
        int piv = k; float mx = fabsf(M[k][k]);
        for (int r = k+1; r < 6; r++) { float vv = fabsf(M[r][k]); if (vv > mx) { mx = vv; piv = r; } }
        if (piv != k)
            for (int j = 0; j < 7; j++) { float tmp = M[k][j]; M[k][j] = M[piv][j]; M[piv][j] = tmp; }
        const float inv = 1.0f / M[k][k];
        for (int r = k+1; r < 6; r++) {
            const float f = M[r][k] * inv;
            for (int j = k; j < 7; j++) M[r][j] -= f * M[k][j];
        }
    }
    float xi[6];
    for (int i = 5; i >= 0; i--) {
        float s = M[i][6];
        for (int j = i+1; j < 6; j++) s -= M[i][j]*xi[j];
        xi[i] = s / M[i][i];
    }
    const float wx = xi[0], wy = xi[1], wz = xi[2];
    const float th2 = wx*wx + wy*wy + wz*wz;
    float A, Bc, Cc;
    if (th2 < 1e-8f) {
        A  = 1.f - th2/6.f;
        Bc = 0.5f - th2/24.f;
        Cc = 1.f/6.f - th2/120.f;
    } else {
        const float th = sqrtf(th2);
        const float s = sinf(th), cth = cosf(th);
        A  = s/th;
        Bc = (1.f - cth)/th2;
        Cc = (th - s)/(th2*th);
    }
    float K[3][3] = {{0.f, -wz, wy}, {wz, 0.f, -wx}, {-wy, wx, 0.f}};
    float K2[3][3];
    for (int i = 0; i < 3; i++)
        for (int j = 0; j < 3; j++)
            K2[i][j] = K[i][0]*K[0][j] + K[i][1]*K[1][j] + K[i][2]*K[2][j];
    float Re[3][3], Vm[3][3];
    for (int i = 0; i < 3; i++)
        for (int j = 0; j < 3; j++) {
            const float eye = (i == j) ? 1.f : 0.f;
            Re[i][j] = eye + A*K[i][j] + Bc*K2[i][j];
            Vm[i][j] = eye + Bc*K[i][j] + Cc*K2[i][j];
        }
    float tt[3];
    for (int i = 0; i < 3; i++)
        tt[i] = Vm[i][0]*xi[3] + Vm[i][1]*xi[4] + Vm[i][2]*xi[5];
    float Pold[16], Pnew[16];
    for (int i = 0; i < 16; i++) Pold[i] = poseb[i];
    for (int j = 0; j < 4; j++) {
        for (int i = 0; i < 3; i++)
            Pnew[i*4+j] = Re[i][0]*Pold[0*4+j] + Re[i][1]*Pold[1*4+j] + Re[i][2]*Pold[2*4+j] + tt[i]*Pold[3*4+j];
        Pnew[3*4+j] = Pold[3*4+j];
    }
    for (int i = 0; i < 16; i++) { poseb[i] = Pnew[i]; outb[i] = Pnew[i]; }
}

// grid dim3(512, B_), 256 threads, 3 (pixel,channel) items per thread.
// Phase-separated: batch loads -> batch math -> batch gathers -> batch compute,
// so ~15 loads/thread are simultaneously in flight. ICP (c==0) is exactly
// item 0 of blocks bid<192 (wave-uniform). Last block per (iter,batch) runs
// the 6x6 solve inline (saves 3 dispatches).
__global__ __launch_bounds__(256)
void accumulate_kernel(const float* __restrict__ Ipad,
                       const float* __restrict__ VN,
                       const float* __restrict__ I1,
                       const float* __restrict__ depth0,
                       const float* __restrict__ depth1,
                       const float* __restrict__ intr,
                       float* __restrict__ poseb_all,
                       float* __restrict__ acc,      // this iteration's acc (B_*32)
                       unsigned int* __restrict__ cnt, // this iteration's counters (B_)
                       float* __restrict__ out) {
    const int b = blockIdx.y;
    float* poseb = poseb_all + b*16;
    const float R00 = poseb[0],  R01 = poseb[1],  R02 = poseb[2],  t0 = poseb[3];
    const float R10 = poseb[4],  R11 = poseb[5],  R12 = poseb[6],  t1 = poseb[7];
    const float R20 = poseb[8],  R21 = poseb[9],  R22 = poseb[10], t2 = poseb[11];
    const float fx = intr[b*4+0], fy = intr[b*4+1], cx = intr[b*4+2], cy = intr[b*4+3];
    const float ifx = 1.0f/fx, ify = 1.0f/fy;
    const float* Ib  = Ipad + (size_t)b*C_*HPLANE_;
    const float* VNb = VN + (size_t)b*HW_*4;
    const float* I1b = I1 + b*C_*HW_;
    const float* d0b = depth0 + b*HW_;
    const float* d1b = depth1 + b*HW_;
    float* accb = acc + b*32;

    float a[27];
#pragma unroll
    for (int i = 0; i < 27; i++) a[i] = 0.f;

    // ---- phase 1: coalesced loads for all items ----
    int gg[3], pp[3], cch[3];
    float d1v[3], d0v[3], i1v[3];
#pragma unroll
    for (int i = 0; i < 3; i++) {
        gg[i] = i*131072 + (int)blockIdx.x*256 + (int)threadIdx.x;
        cch[i] = gg[i] / HW_;
        pp[i] = gg[i] - cch[i]*HW_;
        d1v[i] = d1b[pp[i]];
        d0v[i] = d0b[pp[i]];
        i1v[i] = I1b[gg[i]];
    }

    // ---- phase 2: projection math ----
    float Xs[3], Ys[3], Zs[3], izs[3];
    float w00[3], w10[3], w01[3], w11[3], vm[3];
    int ofs0[3], ofsm[3], ofsp[3];
    int u0icp = 1, v0icp = 1;
#pragma unroll
    for (int i = 0; i < 3; i++) {
        const int h = pp[i] >> 8;
        const int w = pp[i] & 255;
        const float pxv = ((float)w - cx)*ifx;
        const float pyv = ((float)h - cy)*ify;
        const float V1x = pxv*d1v[i], V1y = pyv*d1v[i], V1z = d1v[i];
        const float X0 = R00*V1x + R01*V1y + R02*V1z + t0;
        const float Y0 = R10*V1x + R11*V1y + R12*V1z + t1;
        const float Z0 = R20*V1x + R21*V1y + R22*V1z + t2;
        bool valid = (Z0 > 1e-8f) && (d0v[i] > 0.f) && (d1v[i] > 0.f);
        const float Z = valid ? Z0 : 1.0f;
        const float X = valid ? X0 : 0.0f;
        const float Y = valid ? Y0 : 0.0f;
        const float invz = 1.0f / Z;
        float u = fx*X*invz + cx;
        float v = fy*Y*invz + cy;
        valid = valid && (u > 0.f && u < (float)(W_-1) && v > 0.f && v < (float)(H_-1));
        u = valid ? u : 1.5f;
        v = valid ? v : 1.5f;
        const float u0f = floorf(u), v0f = floorf(v);
        const int u0 = (int)u0f, v0 = (int)v0f;
        const float du = u - u0f, dv = v - v0f;
        w00[i] = (1.f-du)*(1.f-dv); w10[i] = du*(1.f-dv);
        w01[i] = (1.f-du)*dv;       w11[i] = du*dv;
        vm[i] = valid ? 1.f : 0.f;
        Xs[i] = X; Ys[i] = Y; Zs[i] = Z; izs[i] = invz;
        const int chb = cch[i]*HPLANE_;
        ofs0[i] = chb + v0*SP_ + u0;
        ofsm[i] = chb + max(v0-1, 0)*SP_ + u0 + 1;
        ofsp[i] = chb + min(v0+2, H_-1)*SP_ + u0 + 1;
        if (i == 0) { u0icp = u0; v0icp = v0; }
    }

    // ---- phase 3: all gathers ----
    f4a A0[3], A1[3];
    f2a Bm[3], Bp[3];
#pragma unroll
    for (int i = 0; i < 3; i++) {
        A0[i] = *(const f4a*)(Ib + ofs0[i]);
        A1[i] = *(const f4a*)(Ib + ofs0[i] + SP_);
        Bm[i] = *(const f2a*)(Ib + ofsm[i]);
        Bp[i] = *(const f2a*)(Ib + ofsp[i]);
    }
    const bool hasICP = (blockIdx.x < 192);  // == (cch[0]==0), uniform
    f4v VN00, VN10, VN01, VN11;
    if (hasICP) {
        const int i00 = v0icp*W_ + u0icp;
        VN00 = *(const f4v*)(VNb + (size_t)i00*4);
        VN10 = *(const f4v*)(VNb + (size_t)(i00+1)*4);
        VN01 = *(const f4v*)(VNb + (size_t)(i00+W_)*4);
        VN11 = *(const f4v*)(VNb + (size_t)(i00+W_+1)*4);
    }

    // ---- phase 4: photometric compute ----
#pragma unroll
    for (int i = 0; i < 3; i++) {
        const float X = Xs[i], Y = Ys[i], Z = Zs[i], invz = izs[i];
        const float Jp00 = fx*invz, Jp02 = -fx*X*invz*invz;
        const float Jp11 = fy*invz, Jp12 = -fy*Y*invz*invz;
        float Jw0[6], Jw1[6];
        {
            const float Jt_[3][6] = {
                {0.f,  Z, -Y, 1.f, 0.f, 0.f},
                {-Z, 0.f,  X, 0.f, 1.f, 0.f},
                { Y,  -X, 0.f, 0.f, 0.f, 1.f}};
#pragma unroll
            for (int k = 0; k < 6; k++) {
                Jw0[k] = Jp00*Jt_[0][k] + Jp02*Jt_[2][k];
                Jw1[k] = Jp11*Jt_[1][k] + Jp12*Jt_[2][k];
            }
        }
        const float fm0 = A0[i].x, f00 = A0[i].y, f10 = A0[i].z, fp0 = A0[i].w;
        const float fm1 = A1[i].x, f01 = A1[i].y, f11 = A1[i].z, fp1 = A1[i].w;
        const float g0a = Bm[i].x, g0b = Bm[i].y, g1a = Bp[i].x, g1b = Bp[i].y;
        const float I0w = w00[i]*f00 + w10[i]*f10 + w01[i]*f01 + w11[i]*f11;
        const float gx00 = 0.5f*(f10 - fm0);
        const float gx10 = 0.5f*(fp0 - f00);
        const float gx01 = 0.5f*(f11 - fm1);
        const float gx11 = 0.5f*(fp1 - f01);
        const float gy00 = 0.5f*(f01 - g0a);
        const float gy10 = 0.5f*(f11 - g0b);
        const float gy01 = 0.5f*(g1a - f00);
        const float gy11 = 0.5f*(g1b - f10);
        const float gx = w00[i]*gx00 + w10[i]*gx10 + w01[i]*gx01 + w11[i]*gx11;
        const float gy = w00[i]*gy00 + w10[i]*gy10 + w01[i]*gy01 + w11[i]*gy11;
        const float rv = i1v[i] - I0w;
        float Jr[6];
#pragma unroll
        for (int k = 0; k < 6; k++) Jr[k] = gx*Jw0[k] + gy*Jw1[k];
        const float ar = fabsf(rv);
        const float wt = vm[i] * ((ar <= HUBER) ? 1.f : HUBER / fmaxf(ar, 1e-12f));
        int cntk = 0;
#pragma unroll
        for (int i2 = 0; i2 < 6; i2++) {
            const float wJ = wt * Jr[i2];
#pragma unroll
            for (int j2 = i2; j2 < 6; j2++) a[cntk++] += wJ * Jr[j2];
            a[21+i2] += wJ * rv;
        }
    }

    // ---- phase 5: ICP (uniform branch) ----
    if (hasICP) {
        const int h = pp[0] >> 8;
        const int w = pp[0] & 255;
        const float pxv = ((float)w - cx)*ifx;
        const float pyv = ((float)h - cy)*ify;
        const float V1x = pxv*d1v[0], V1y = pyv*d1v[0], V1z = d1v[0];
        const float X = Xs[0], Y = Ys[0], Z = Zs[0];
        const float dc00 = VN00.w, dc10 = VN10.w, dc01 = VN01.w, dc11 = VN11.w;
        const float pxu0 = ((float)u0icp - cx)*ifx, pxu1 = ((float)(u0icp+1) - cx)*ifx;
        const float pyv0 = ((float)v0icp - cy)*ify, pyv1 = ((float)(v0icp+1) - cy)*ify;
        const float rVx = w00[0]*pxu0*dc00 + w10[0]*pxu1*dc10 + w01[0]*pxu0*dc01 + w11[0]*pxu1*dc11;
        const float rVy = w00[0]*pyv0*dc00 + w10[0]*pyv0*dc10 + w01[0]*pyv1*dc01 + w11[0]*pyv1*dc11;
        const float rVz = w00[0]*dc00 + w10[0]*dc10 + w01[0]*dc01 + w11[0]*dc11;
        const float rN0 = w00[0]*VN00.x + w10[0]*VN10.x + w01[0]*VN01.x + w11[0]*VN11.x;
        const float rN1 = w00[0]*VN00.y + w10[0]*VN10.y + w01[0]*VN01.y + w11[0]*VN11.y;
        const float rN2 = w00[0]*VN00.z + w10[0]*VN10.z + w01[0]*VN01.z + w11[0]*VN11.z;
        const float dfx = X - rVx, dfy = Y - rVy, dfz = Z - rVz;
        const float dn = sqrtf(dfx*dfx + dfy*dfy + dfz*dfz + 1e-12f);
        const bool occ = dn > 0.1f;
        const float res = rN0*dfx + rN1*dfy + rN2*dfz;
        const float NtC0 = rN0*R00 + rN1*R10 + rN2*R20;
        const float NtC1 = rN0*R01 + rN1*R11 + rN2*R21;
        const float NtC2 = rN0*R02 + rN1*R12 + rN2*R22;
        const float Jr0 = NtC1*V1z - NtC2*V1y;
        const float Jr1 = NtC2*V1x - NtC0*V1z;
        const float Jr2 = NtC0*V1y - NtC1*V1x;
        const float sd0 = d1v[0] * (5.5f/525.0f);
        const float sd2 = d1v[0] * d1v[0] * (0.4f/(525.0f*1.2f));
        const float cov = (NtC0*NtC0 + NtC1*NtC1)*sd0*sd0 + NtC2*NtC2*sd2*sd2;
        const float sigma = sqrtf(cov + 1e-8f);
        const float invs = 1.0f/(sigma + 1e-8f);
        const float rZ = occ ? 1e-6f : res*invs;
        float Jr[6];
        Jr[0] = GEOMW * (-Jr0*invs);
        Jr[1] = GEOMW * (-Jr1*invs);
        Jr[2] = GEOMW * (-Jr2*invs);
        Jr[3] = GEOMW * ( NtC0*invs);
        Jr[4] = GEOMW * ( NtC1*invs);
        Jr[5] = GEOMW * ( NtC2*invs);
        const float rv = -GEOMW * rZ;
        const float ar = fabsf(rv);
        const float wt = vm[0] * ((ar <= HUBER) ? 1.f : HUBER / fmaxf(ar, 1e-12f));
        int cntk = 0;
#pragma unroll
        for (int i2 = 0; i2 < 6; i2++) {
            const float wJ = wt * Jr[i2];
#pragma unroll
            for (int j2 = i2; j2 < 6; j2++) a[cntk++] += wJ * Jr[j2];
            a[21+i2] += wJ * rv;
        }
    }

    // ---- reduction: wave shuffle -> LDS -> 27 atomics ----
    __shared__ float red[4][27];
    __shared__ unsigned s_last;
    const int wid  = threadIdx.x >> 6;
    const int lane = threadIdx.x & 63;
#pragma unroll
    for (int k = 0; k < 27; k++) {
        float val = a[k];
        for (int off = 32; off > 0; off >>= 1)
            val += __shfl_down(val, off, 64);
        if (lane == 0) red[wid][k] = val;
    }
    __syncthreads();
    if (threadIdx.x < 27) {
        const int k = threadIdx.x;
        atomicAdd(&accb[k], red[0][k] + red[1][k] + red[2][k] + red[3][k]);
    }
    __syncthreads();   // drains the atomics (barrier implies vmcnt(0))
    if (threadIdx.x == 0) {
        __threadfence();
        const unsigned old = atomicAdd(&cnt[b], 1u);
        s_last = (old == (unsigned)(gridDim.x - 1)) ? 1u : 0u;
    }
    __syncthreads();
    if (s_last && threadIdx.x == 0) {
        solve_one(accb, poseb, out + b*16);
    }
}

extern "C" void kernel_launch(void* const* d_in, const int* in_sizes, int n_in,
                              void* d_out, int out_size, void* d_ws, size_t ws_size,
                              hipStream_t stream) {
    const float* pose0  = (const float*)d_in[0];
    const float* I0     = (const float*)d_in[1];
    const float* I1     = (const float*)d_in[2];
    const float* intr   = (const float*)d_in[5];
    const float* depth0 = (const float*)d_in[6];
    const float* depth1 = (const float*)d_in[7];
    float* ws    = (float*)d_ws;
    float* Ipad  = ws;
    float* VN    = Ipad + IPAD_SZ;
    float* acc   = VN + VN_SZ;
    unsigned int* cnt = (unsigned int*)(acc + ACC_SZ);
    float* poseb = (float*)(cnt + CNT_SZ);
    float* out   = (float*)d_out;

    precompute_kernel<<<(B_*HW_ + 255)/256, 256, 0, stream>>>(
        I0, depth0, intr, pose0, Ipad, VN, acc, cnt, poseb);
    for (int it = 0; it < 3; it++) {
        accumulate_kernel<<<dim3(512, B_), 256, 0, stream>>>(
            Ipad, VN, I1, depth0, depth1, intr, poseb,
            acc + it*B_*32, cnt + it*B_, out);
    }
}

// Round 8
// 159.254 us; speedup vs baseline: 1.9463x; 1.9463x over previous
//
#include <hip/hip_runtime.h>
#include <math.h>

#define B_ 4
#define C_ 8
#define H_ 192
#define W_ 256
#define HW_ (H_*W_)
#define GEOMW 0.01f
#define HUBER 0.5f
#define LMEPS 1e-6f

// ws layout (floats)
#define N0_SZ  (B_*3*HW_)
#define ACC_SZ (3*B_*32)
#define POSE_SZ (B_*16)

// 4-byte-aligned vector types (bilinear taps are only 4B aligned)
typedef float f4a __attribute__((ext_vector_type(4), aligned(4)));
typedef float f2a __attribute__((ext_vector_type(2), aligned(4)));

// precompute normals + zero acc + copy pose0 -> poseb (all init in one dispatch)
__global__ void precompute_kernel(const float* __restrict__ depth0,
                                  const float* __restrict__ intr,
                                  const float* __restrict__ pose0,
                                  float* __restrict__ N0,
                                  float* __restrict__ acc,
                                  float* __restrict__ poseb) {
    int idx = blockIdx.x * blockDim.x + threadIdx.x;
    if (idx < ACC_SZ) acc[idx] = 0.f;
    if (idx < POSE_SZ) poseb[idx] = pose0[idx];
    if (idx >= B_ * HW_) return;
    int b = idx / HW_;
    int p = idx - b * HW_;
    int h = p >> 8;
    int w = p & 255;
    float fx = intr[b*4+0], fy = intr[b*4+1], cx = intr[b*4+2], cy = intr[b*4+3];
    const float* d = depth0 + b * HW_;
    int wl = max(w-1, 0), wr = min(w+1, W_-1);
    int hu = max(h-1, 0), hd = min(h+1, H_-1);
    float dr = d[h*W_ + wr], dl = d[h*W_ + wl];
    float dd = d[hd*W_ + w], du_ = d[hu*W_ + w];
    float pxr = ((float)wr - cx)/fx, pxl = ((float)wl - cx)/fx;
    float pyh = ((float)h  - cy)/fy;
    float pxw = ((float)w  - cx)/fx;
    float pyd = ((float)hd - cy)/fy, pyu = ((float)hu - cy)/fy;
    float dxx = 0.5f*(pxr*dr - pxl*dl), dxy = 0.5f*(pyh*dr - pyh*dl), dxz = 0.5f*(dr - dl);
    float dyx = 0.5f*(pxw*dd - pxw*du_), dyy = 0.5f*(pyd*dd - pyu*du_), dyz = 0.5f*(dd - du_);
    float n0 = dxy*dyz - dxz*dyy;
    float n1 = dxz*dyx - dxx*dyz;
    float n2 = dxx*dyy - dxy*dyx;
    float inv = 1.0f / sqrtf(n0*n0 + n1*n1 + n2*n2 + 1e-12f);
    N0[(b*3+0)*HW_ + p] = n0*inv;
    N0[(b*3+1)*HW_ + p] = n1*inv;
    N0[(b*3+2)*HW_ + p] = n2*inv;
}

// Round-4 structure (6 items/thread, grid dim3(256,B_), branchy skip) + XCD
// band swizzle: blockIdx.x%8 picks a 24-row image band; blocks land on XCDs
// round-robin, so each XCD's L2 only sees ~550 KB (band slice of all inputs)
// instead of the full 16 MB batch working set. Reprojection offsets are
// +-2 px, so gathers stay in-band.
__global__ __launch_bounds__(256)
void accumulate_kernel(const float* __restrict__ I0,
                       const float* __restrict__ I1,
                       const float* __restrict__ depth0,
                       const float* __restrict__ depth1,
                       const float* __restrict__ intr,
                       const float* __restrict__ N0,
                       const float* __restrict__ poseb,
                       float* __restrict__ acc) {
    const int b = blockIdx.y;
    const float* P = poseb + b*16;
    const float R00 = P[0],  R01 = P[1],  R02 = P[2],  t0 = P[3];
    const float R10 = P[4],  R11 = P[5],  R12 = P[6],  t1 = P[7];
    const float R20 = P[8],  R21 = P[9],  R22 = P[10], t2 = P[11];
    const float fx = intr[b*4+0], fy = intr[b*4+1], cx = intr[b*4+2], cy = intr[b*4+3];
    const float ifx = 1.0f/fx, ify = 1.0f/fy;
    const float* I0b = I0 + b*C_*HW_;
    const float* I1b = I1 + b*C_*HW_;
    const float* d0b = depth0 + b*HW_;
    const float* d1b = depth1 + b*HW_;
    const float* N0b = N0 + b*3*HW_;
    float* accb = acc + b*32;

    const int band = (int)blockIdx.x & 7;       // -> XCD via round-robin dispatch
    const int seg  = (int)blockIdx.x >> 3;      // 32 segments per band
    const int pbase = band * 6144;              // 24 rows * 256 px

    float a[27];
#pragma unroll
    for (int i = 0; i < 27; i++) a[i] = 0.f;

#pragma unroll 2
    for (int item = 0; item < 6; ++item) {
        // g_local in [0, 49152): 8 channels x 6144 band pixels
        const int gl = item*8192 + seg*256 + (int)threadIdx.x;
        const int c = gl / 6144;
        const int pl = gl - c*6144;
        const int p = pbase + pl;
        const int h = p >> 8;         // W_ = 256
        const int w = p & 255;
        const float d1v = d1b[p];
        const float d0v = d0b[p];
        const float pxv = ((float)w - cx)*ifx;
        const float pyv = ((float)h - cy)*ify;
        const float V1x = pxv*d1v, V1y = pyv*d1v, V1z = d1v;
        const float X = R00*V1x + R01*V1y + R02*V1z + t0;
        const float Y = R10*V1x + R11*V1y + R12*V1z + t1;
        const float Z = R20*V1x + R21*V1y + R22*V1z + t2;

        bool valid = (Z > 1e-8f) && (d0v > 0.f) && (d1v > 0.f);
        float u = 0.f, v = 0.f, invz = 1.f;
        if (valid) {
            invz = 1.0f / Z;
            u = fx*X*invz + cx;
            v = fy*Y*invz + cy;
            valid = (u > 0.f && u < (float)(W_-1) && v > 0.f && v < (float)(H_-1));
        }
        if (!valid) continue;

        const float u0f = floorf(u), v0f = floorf(v);
        const int u0 = (int)u0f, v0 = (int)v0f;
        const float du = u - u0f, dv = v - v0f;
        const float w00 = (1.f-du)*(1.f-dv), w10 = du*(1.f-dv);
        const float w01 = (1.f-du)*dv,       w11 = du*dv;
        const int i00 = v0*W_ + u0, i01 = i00 + W_;

        const float Jp00 = fx*invz, Jp02 = -fx*X*invz*invz;
        const float Jp11 = fy*invz, Jp12 = -fy*Y*invz*invz;
        float Jw0[6], Jw1[6];
        {
            const float Jt_[3][6] = {
                {0.f,  Z, -Y, 1.f, 0.f, 0.f},
                {-Z, 0.f,  X, 0.f, 1.f, 0.f},
                { Y,  -X, 0.f, 0.f, 0.f, 1.f}};
#pragma unroll
            for (int k = 0; k < 6; k++) {
                Jw0[k] = Jp00*Jt_[0][k] + Jp02*Jt_[2][k];
                Jw1[k] = Jp11*Jt_[1][k] + Jp12*Jt_[2][k];
            }
        }

        // ---- photometric channel c ----
        {
            const float* Ic = I0b + c*HW_;
            const int r0 = v0*W_, r1 = r0 + W_;
            const int rm = max(v0-1,0)*W_, rp = min(v0+2,H_-1)*W_;
            float fm0,f00,f10,fp0, fm1,f01,f11,fp1, g0a,g0b,g1a,g1b;
            if (u0 >= 1 && u0 <= W_-3) {
                const f4a A0 = *(const f4a*)(Ic + r0 + u0 - 1);
                const f4a A1 = *(const f4a*)(Ic + r1 + u0 - 1);
                const f2a Bm = *(const f2a*)(Ic + rm + u0);
                const f2a Bp = *(const f2a*)(Ic + rp + u0);
                fm0=A0.x; f00=A0.y; f10=A0.z; fp0=A0.w;
                fm1=A1.x; f01=A1.y; f11=A1.z; fp1=A1.w;
                g0a=Bm.x; g0b=Bm.y; g1a=Bp.x; g1b=Bp.y;
            } else {
                const int um = max(u0-1, 0), up = min(u0+2, W_-1);
                f00=Ic[r0+u0]; f10=Ic[r0+u0+1]; f01=Ic[r1+u0]; f11=Ic[r1+u0+1];
                fm0=Ic[r0+um]; fp0=Ic[r0+up];   fm1=Ic[r1+um]; fp1=Ic[r1+up];
                g0a=Ic[rm+u0]; g0b=Ic[rm+u0+1]; g1a=Ic[rp+u0]; g1b=Ic[rp+u0+1];
            }
            const float I0w = w00*f00 + w10*f10 + w01*f01 + w11*f11;
            const float gx00 = 0.5f*(f10 - fm0);
            const float gx10 = 0.5f*(fp0 - f00);
            const float gx01 = 0.5f*(f11 - fm1);
            const float gx11 = 0.5f*(fp1 - f01);
            const float gy00 = 0.5f*(f01 - g0a);
            const float gy10 = 0.5f*(f11 - g0b);
            const float gy01 = 0.5f*(g1a - f00);
            const float gy11 = 0.5f*(g1b - f10);
            const float gx = w00*gx00 + w10*gx10 + w01*gx01 + w11*gx11;
            const float gy = w00*gy00 + w10*gy10 + w01*gy01 + w11*gy11;
            const float rv = I1b[c*HW_ + p] - I0w;
            float Jr[6];
#pragma unroll
            for (int k = 0; k < 6; k++) Jr[k] = gx*Jw0[k] + gy*Jw1[k];
            const float ar = fabsf(rv);
            const float wt = (ar <= HUBER) ? 1.f : HUBER / fmaxf(ar, 1e-12f);
            int cnt = 0;
#pragma unroll
            for (int i2 = 0; i2 < 6; i2++) {
                const float wJ = wt * Jr[i2];
#pragma unroll
                for (int j2 = i2; j2 < 6; j2++) a[cnt++] += wJ * Jr[j2];
                a[21+i2] += wJ * rv;
            }
        }

        // ---- ICP channel (c==0 items only) ----
        if (c == 0) {
            const f2a D0 = *(const f2a*)(d0b + i00);
            const f2a D1 = *(const f2a*)(d0b + i01);
            const float dc00 = D0.x, dc10 = D0.y, dc01 = D1.x, dc11 = D1.y;
            const float pxu0 = ((float)u0 - cx)*ifx, pxu1 = ((float)(u0+1) - cx)*ifx;
            const float pyv0 = ((float)v0 - cy)*ify, pyv1 = ((float)(v0+1) - cy)*ify;
            const float rVx = w00*pxu0*dc00 + w10*pxu1*dc10 + w01*pxu0*dc01 + w11*pxu1*dc11;
            const float rVy = w00*pyv0*dc00 + w10*pyv0*dc10 + w01*pyv1*dc01 + w11*pyv1*dc11;
            const float rVz = w00*dc00 + w10*dc10 + w01*dc01 + w11*dc11;
            float rN[3];
#pragma unroll
            for (int cc = 0; cc < 3; cc++) {
                const float* Nc = N0b + cc*HW_;
                const f2a Na = *(const f2a*)(Nc + i00);
                const f2a Nb = *(const f2a*)(Nc + i01);
                rN[cc] = w00*Na.x + w10*Na.y + w01*Nb.x + w11*Nb.y;
            }
            const float dfx = X - rVx, dfy = Y - rVy, dfz = Z - rVz;
            const float dn = sqrtf(dfx*dfx + dfy*dfy + dfz*dfz + 1e-12f);
            const bool occ = dn > 0.1f;
            const float res = rN[0]*dfx + rN[1]*dfy + rN[2]*dfz;
            const float NtC0 = rN[0]*R00 + rN[1]*R10 + rN[2]*R20;
            const float NtC1 = rN[0]*R01 + rN[1]*R11 + rN[2]*R21;
            const float NtC2 = rN[0]*R02 + rN[1]*R12 + rN[2]*R22;
            const float Jr0 = NtC1*V1z - NtC2*V1y;
            const float Jr1 = NtC2*V1x - NtC0*V1z;
            const float Jr2 = NtC0*V1y - NtC1*V1x;
            const float sd0 = d1v * (5.5f/525.0f);
            const float sd2 = d1v * d1v * (0.4f/(525.0f*1.2f));
            const float cov = (NtC0*NtC0 + NtC1*NtC1)*sd0*sd0 + NtC2*NtC2*sd2*sd2;
            const float sigma = sqrtf(cov + 1e-8f);
            const float invs = 1.0f/(sigma + 1e-8f);
            const float rZ = occ ? 1e-6f : res*invs;
            float Jr[6];
            Jr[0] = GEOMW * (-Jr0*invs);
            Jr[1] = GEOMW * (-Jr1*invs);
            Jr[2] = GEOMW * (-Jr2*invs);
            Jr[3] = GEOMW * ( NtC0*invs);
            Jr[4] = GEOMW * ( NtC1*invs);
            Jr[5] = GEOMW * ( NtC2*invs);
            const float rv = -GEOMW * rZ;
            const float ar = fabsf(rv);
            const float wt = (ar <= HUBER) ? 1.f : HUBER / fmaxf(ar, 1e-12f);
            int cnt = 0;
#pragma unroll
            for (int i2 = 0; i2 < 6; i2++) {
                const float wJ = wt * Jr[i2];
#pragma unroll
                for (int j2 = i2; j2 < 6; j2++) a[cnt++] += wJ * Jr[j2];
                a[21+i2] += wJ * rv;
            }
        }
    }

    // reduction: wave shuffle -> LDS per wave -> 27 atomics per block
    __shared__ float red[4][27];
    const int wid  = threadIdx.x >> 6;
    const int lane = threadIdx.x & 63;
#pragma unroll
    for (int k = 0; k < 27; k++) {
        float val = a[k];
        for (int off = 32; off > 0; off >>= 1)
            val += __shfl_down(val, off, 64);
        if (lane == 0) red[wid][k] = val;
    }
    __syncthreads();
    if (threadIdx.x < 27) {
        const int k = threadIdx.x;
        atomicAdd(&accb[k], red[0][k] + red[1][k] + red[2][k] + red[3][k]);
    }
}

__global__ void solve_kernel(const float* __restrict__ acc,
                             float* __restrict__ poseb,
                             float* __restrict__ out) {
    int b = threadIdx.x;
    if (b >= B_) return;
    const float* a = acc + b*32;
    float M[6][7];
    {
        int cnt = 0;
        float Hm[6][6];
        for (int i = 0; i < 6; i++)
            for (int j = i; j < 6; j++) { Hm[i][j] = a[cnt]; Hm[j][i] = a[cnt]; cnt++; }
        for (int i = 0; i < 6; i++) {
            for (int j = 0; j < 6; j++) M[i][j] = Hm[i][j];
            M[i][i] += LMEPS;
            M[i][6] = a[21+i];
        }
    }
    for (int k = 0; k < 6; k++) {
        int piv = k; float mx = fabsf(M[k][k]);
        for (int r = k+1; r < 6; r++) { float vv = fabsf(M[r][k]); if (vv > mx) { mx = vv; piv = r; } }
        if (piv != k)
            for (int j = 0; j < 7; j++) { float tmp = M[k][j]; M[k][j] = M[piv][j]; M[piv][j] = tmp; }
        const float inv = 1.0f / M[k][k];
        for (int r = k+1; r < 6; r++) {
            const float f = M[r][k] * inv;
            for (int j = k; j < 7; j++) M[r][j] -= f * M[k][j];
        }
    }
    float xi[6];
    for (int i = 5; i >= 0; i--) {
        float s = M[i][6];
        for (int j = i+1; j < 6; j++) s -= M[i][j]*xi[j];
        xi[i] = s / M[i][i];
    }
    const float wx = xi[0], wy = xi[1], wz = xi[2];
    const float th2 = wx*wx + wy*wy + wz*wz;
    float A, Bc, Cc;
    if (th2 < 1e-8f) {
        A  = 1.f - th2/6.f;
        Bc = 0.5f - th2/24.f;
        Cc = 1.f/6.f - th2/120.f;
    } else {
        const float th = sqrtf(th2);
        const float s = sinf(th), cth = cosf(th);
        A  = s/th;
        Bc = (1.f - cth)/th2;
        Cc = (th - s)/(th2*th);
    }
    float K[3][3] = {{0.f, -wz, wy}, {wz, 0.f, -wx}, {-wy, wx, 0.f}};
    float K2[3][3];
    for (int i = 0; i < 3; i++)
        for (int j = 0; j < 3; j++)
            K2[i][j] = K[i][0]*K[0][j] + K[i][1]*K[1][j] + K[i][2]*K[2][j];
    float Re[3][3], Vm[3][3];
    for (int i = 0; i < 3; i++)
        for (int j = 0; j < 3; j++) {
            const float eye = (i == j) ? 1.f : 0.f;
            Re[i][j] = eye + A*K[i][j] + Bc*K2[i][j];
            Vm[i][j] = eye + Bc*K[i][j] + Cc*K2[i][j];
        }
    float tt[3];
    for (int i = 0; i < 3; i++)
        tt[i] = Vm[i][0]*xi[3] + Vm[i][1]*xi[4] + Vm[i][2]*xi[5];
    float Pold[16], Pnew[16];
    for (int i = 0; i < 16; i++) Pold[i] = poseb[b*16 + i];
    for (int j = 0; j < 4; j++) {
        for (int i = 0; i < 3; i++)
            Pnew[i*4+j] = Re[i][0]*Pold[0*4+j] + Re[i][1]*Pold[1*4+j] + Re[i][2]*Pold[2*4+j] + tt[i]*Pold[3*4+j];
        Pnew[3*4+j] = Pold[3*4+j];
    }
    for (int i = 0; i < 16; i++) { poseb[b*16 + i] = Pnew[i]; out[b*16 + i] = Pnew[i]; }
}

extern "C" void kernel_launch(void* const* d_in, const int* in_sizes, int n_in,
                              void* d_out, int out_size, void* d_ws, size_t ws_size,
                              hipStream_t stream) {
    const float* pose0  = (const float*)d_in[0];
    const float* I0     = (const float*)d_in[1];
    const float* I1     = (const float*)d_in[2];
    const float* intr   = (const float*)d_in[5];
    const float* depth0 = (const float*)d_in[6];
    const float* depth1 = (const float*)d_in[7];
    float* ws    = (float*)d_ws;
    float* N0    = ws;
    float* acc   = ws + N0_SZ;
    float* poseb = acc + ACC_SZ;
    float* out   = (float*)d_out;

    precompute_kernel<<<(B_*HW_ + 255)/256, 256, 0, stream>>>(depth0, intr, pose0, N0, acc, poseb);
    for (int it = 0; it < 3; it++) {
        accumulate_kernel<<<dim3(256, B_), 256, 0, stream>>>(
            I0, I1, depth0, depth1, intr, N0, poseb, acc + it*B_*32);
        solve_kernel<<<1, 64, 0, stream>>>(acc + it*B_*32, poseb, out);
    }
}